// Round 6
// baseline (1549.256 us; speedup 1.0000x reference)
//
#include <hip/hip_runtime.h>

#define Bz 8
#define T1z 13
#define Tz 12
#define Vz 20000
#define Ez 512
#define Dz 512
#define Kz 512
#define Cz 2048
#define Pz 64

// bf16 element offsets in the converted-weight pool
#define NB16   18104320
#define O_WIH  10240000
#define O_WHH  15482880
#define O_WS   16531456
#define O_WHC  17580032
#define O_WHS  17842176

__device__ __forceinline__ unsigned short f2b(float x) {
    unsigned u = __float_as_uint(x);
    return (unsigned short)((u + 0x7fffu + ((u >> 16) & 1u)) >> 16);
}
__device__ __forceinline__ float bLO(unsigned u) { return __uint_as_float(u << 16); }
__device__ __forceinline__ float bHI(unsigned u) { return __uint_as_float(u & 0xffff0000u); }

__device__ __forceinline__ float waveReduce(float v) {
    #pragma unroll
    for (int off = 32; off > 0; off >>= 1) v += __shfl_xor(v, off);
    return v;
}
__device__ __forceinline__ float sigf(float x) { return 1.0f / (1.0f + expf(-x)); }

// ---- prep: weights->bf16 + vmean + tail outputs ----
__global__ __launch_bounds__(256) void k_prep(
    const float* __restrict__ W_fc, const float* __restrict__ W_ih,
    const float* __restrict__ W_hh, const float* __restrict__ W_s,
    const float* __restrict__ W_hc, const float* __restrict__ W_hs,
    const float* __restrict__ enc, const int* __restrict__ caps,
    const int* __restrict__ caplen,
    unsigned short* __restrict__ wb, float* __restrict__ vmean,
    float* __restrict__ out) {
    int blk = blockIdx.x, tid = threadIdx.x;
    if (blk < 4096) {
        int gid = blk * 256 + tid;
        #pragma unroll
        for (int it = 0; it < 5; it++) {
            int idx4 = gid + it * 1048576;
            if (idx4 < NB16 / 4) {
                int e = idx4 * 4;
                const float* src; int off;
                if (e < O_WIH)      { src = W_fc; off = e; }
                else if (e < O_WHH) { src = W_ih; off = e - O_WIH; }
                else if (e < O_WS)  { src = W_hh; off = e - O_WHH; }
                else if (e < O_WHC) { src = W_s;  off = e - O_WS; }
                else if (e < O_WHS) { src = W_hc; off = e - O_WHC; }
                else                { src = W_hs; off = e - O_WHS; }
                float4 f = *(const float4*)(src + off);
                ushort4 o = { f2b(f.x), f2b(f.y), f2b(f.z), f2b(f.w) };
                *(ushort4*)(wb + e) = o;
            }
        }
    } else if (blk < 4352) {
        int wave = tid >> 6, lane = tid & 63;
        int base = (blk - 4096) * 64 + wave * 16;
        #pragma unroll
        for (int r = 0; r < 16; r++) {
            int row = base + r;
            float v = enc[(size_t)row * 64 + lane];
            v = waveReduce(v);
            if (lane == 0) vmean[row] = v * (1.0f / 64.0f);
        }
    } else {
        const int base = Bz * Tz * Vz;
        const int nCap = Bz * T1z, nLen = Bz, nAlp = Bz * Tz * Pz;
        for (int idx = tid; idx < nCap + nLen + nAlp + Bz; idx += 256) {
            float val;
            if (idx < nCap) val = (float)caps[idx];
            else if (idx < nCap + nLen) val = (float)(caplen[idx - nCap] - 1);
            else if (idx < nCap + nLen + nAlp) val = 0.0f;
            else val = (float)(idx - (nCap + nLen + nAlp));
            out[base + idx] = val;
        }
    }
}

// ---- h0, c0 ----
__global__ __launch_bounds__(256) void k_init(
    const float* __restrict__ vmean,
    const float* __restrict__ Wh, const float* __restrict__ bh,
    const float* __restrict__ Wc, const float* __restrict__ bc,
    float* __restrict__ h, float* __restrict__ c) {
    __shared__ float sm[2048];
    int blk = blockIdx.x, tid = threadIdx.x;
    int wave = tid >> 6, lane = tid & 63;
    int which = blk >> 7, b = (blk >> 4) & 7, d0 = (blk & 15) * 32;
    #pragma unroll
    for (int i = 0; i < 8; i++) sm[tid + i * 256] = vmean[b * Cz + tid + i * 256];
    __syncthreads();
    const float* W = which ? Wc : Wh;
    const float4* vm4 = (const float4*)sm;
    #pragma unroll
    for (int r = 0; r < 8; r++) {
        int d = d0 + wave * 8 + r;
        const float4* W4 = (const float4*)(W + (size_t)d * Cz);
        float acc = 0.0f;
        #pragma unroll
        for (int i = 0; i < 8; i++) {
            float4 wv = W4[i * 64 + lane];
            float4 xv = vm4[i * 64 + lane];
            acc = fmaf(wv.x, xv.x, acc); acc = fmaf(wv.y, xv.y, acc);
            acc = fmaf(wv.z, xv.z, acc); acc = fmaf(wv.w, xv.w, acc);
        }
        acc = waveReduce(acc);
        if (lane == 0) {
            if (which) c[b * Dz + d] = acc + bc[d];
            else       h[b * Dz + d] = acc + bh[d];
        }
    }
}

// ---- s2: qc/qs full GEMV, bias included, no atomics (16 blocks) ----
__global__ __launch_bounds__(256) void k_qcqs(
    const float* __restrict__ h, const unsigned short* __restrict__ wb,
    const float* __restrict__ b_c, const float* __restrict__ b_s,
    float* __restrict__ qc, float* __restrict__ qs) {
    __shared__ float hL[4096];
    __shared__ float pt[2048];
    int blk = blockIdx.x, tid = threadIdx.x;
    int which = blk >> 3, k0 = (blk & 7) * 64;
    #pragma unroll
    for (int i = 0; i < 16; i++) hL[tid + i * 256] = h[tid + i * 256];
    __syncthreads();
    const unsigned short* W = wb + (which ? O_WHS : O_WHC);
    int ds = tid >> 6, kl = tid & 63;
    int k = k0 + kl;
    float acc[8] = {};
    int d0 = ds * 128;
    #pragma unroll 4
    for (int dd = 0; dd < 128; dd++) {
        int d = d0 + dd;
        float w = bLO((unsigned)W[(size_t)d * Kz + k] << 16 >> 16 | ((unsigned)W[(size_t)d * Kz + k] << 16));
        // simpler: decode bf16 scalar
        w = __uint_as_float(((unsigned)W[(size_t)d * Kz + k]) << 16);
        #pragma unroll
        for (int b = 0; b < 8; b++) acc[b] = fmaf(hL[b * 512 + d], w, acc[b]);
    }
    #pragma unroll
    for (int b = 0; b < 8; b++) pt[ds * 512 + kl * 8 + b] = acc[b];
    __syncthreads();
    if (tid < 64) {
        const float* bias = which ? b_s : b_c;
        float bv = bias[k0 + tid];
        float* q = which ? qs : qc;
        #pragma unroll
        for (int b = 0; b < 8; b++) {
            float s = pt[tid * 8 + b] + pt[512 + tid * 8 + b]
                    + pt[1024 + tid * 8 + b] + pt[1536 + tid * 8 + b];
            q[b * Kz + k0 + tid] = s + bv;
        }
    }
}

// ---- s2: gates emb/h partial: geh[b][j] = W_ih[:, :512]@emb + W_hh@h + biases ----
__global__ __launch_bounds__(256) void k_geh(
    const float* __restrict__ h, const float* __restrict__ emb,
    const int* __restrict__ caps, const unsigned short* __restrict__ wb,
    const float* __restrict__ b_ih, const float* __restrict__ b_hh,
    float* __restrict__ geh, int t) {
    int blk = blockIdx.x, tid = threadIdx.x;
    int wave = tid >> 6, lane = tid & 63;
    int j = blk * 4 + wave;
    int bb = lane >> 3, e8 = lane & 7;
    int tok = caps[bb * T1z + t];
    const uint4* Wih4 = (const uint4*)(wb + O_WIH + (size_t)j * 2560);
    const uint4* Whh4 = (const uint4*)(wb + O_WHH + (size_t)j * 512);
    const float4* em4 = (const float4*)(emb + (size_t)tok * Ez);
    const float4* h4  = (const float4*)(h + bb * Dz);
    float acc = 0.0f;
    #pragma unroll
    for (int i = 0; i < 8; i++) {
        uint4 w = Wih4[i * 8 + e8];
        float4 x0 = em4[(i * 8 + e8) * 2];
        float4 x1 = em4[(i * 8 + e8) * 2 + 1];
        acc = fmaf(x0.x, bLO(w.x), acc); acc = fmaf(x0.y, bHI(w.x), acc);
        acc = fmaf(x0.z, bLO(w.y), acc); acc = fmaf(x0.w, bHI(w.y), acc);
        acc = fmaf(x1.x, bLO(w.z), acc); acc = fmaf(x1.y, bHI(w.z), acc);
        acc = fmaf(x1.z, bLO(w.w), acc); acc = fmaf(x1.w, bHI(w.w), acc);
    }
    #pragma unroll
    for (int i = 0; i < 8; i++) {
        uint4 w = Whh4[i * 8 + e8];
        float4 x0 = h4[(i * 8 + e8) * 2];
        float4 x1 = h4[(i * 8 + e8) * 2 + 1];
        acc = fmaf(x0.x, bLO(w.x), acc); acc = fmaf(x0.y, bHI(w.x), acc);
        acc = fmaf(x0.z, bLO(w.y), acc); acc = fmaf(x0.w, bHI(w.y), acc);
        acc = fmaf(x1.x, bLO(w.z), acc); acc = fmaf(x1.y, bHI(w.z), acc);
        acc = fmaf(x1.z, bLO(w.w), acc); acc = fmaf(x1.w, bHI(w.w), acc);
    }
    acc += __shfl_xor(acc, 1);
    acc += __shfl_xor(acc, 2);
    acc += __shfl_xor(acc, 4);
    if (e8 == 0) geh[bb * 2048 + j] = acc + b_ih[j] + b_hh[j];
}

// ---- s2: preds for timestep tt (full vocab) ----
__global__ __launch_bounds__(256) void k_preds(
    const float* __restrict__ h, const unsigned short* __restrict__ wb,
    const float* __restrict__ b_fc, float* __restrict__ out, int tt) {
    int lane = threadIdx.x & 63;
    int gw = blockIdx.x * 4 + (threadIdx.x >> 6);
    int bb = lane >> 3, d8 = lane & 7;
    const float4* h4 = (const float4*)(h + bb * Dz);
    float4 hreg[16];
    #pragma unroll
    for (int i = 0; i < 8; i++) {
        hreg[2 * i]     = h4[i * 16 + d8 * 2];
        hreg[2 * i + 1] = h4[i * 16 + d8 * 2 + 1];
    }
    int v0 = gw * 4;
    #pragma unroll
    for (int j = 0; j < 4; j++) {
        int v = v0 + j;
        if (v < Vz) {
            const uint4* W4 = (const uint4*)(wb + (size_t)v * Dz);
            float acc = 0.0f;
            #pragma unroll
            for (int i = 0; i < 8; i++) {
                uint4 w = W4[i * 8 + d8];
                float4 ha = hreg[2 * i], hb2 = hreg[2 * i + 1];
                acc = fmaf(ha.x, bLO(w.x), acc);  acc = fmaf(ha.y, bHI(w.x), acc);
                acc = fmaf(ha.z, bLO(w.y), acc);  acc = fmaf(ha.w, bHI(w.y), acc);
                acc = fmaf(hb2.x, bLO(w.z), acc); acc = fmaf(hb2.y, bHI(w.z), acc);
                acc = fmaf(hb2.z, bLO(w.w), acc); acc = fmaf(hb2.w, bHI(w.w), acc);
            }
            acc += __shfl_xor(acc, 1);
            acc += __shfl_xor(acc, 2);
            acc += __shfl_xor(acc, 4);
            if (d8 == 0) out[((size_t)bb * Tz + tt) * Vz + v] = acc + b_fc[v];
        }
    }
}

// ---- k2: channel attention + batch softmax -> beta, abf = bf16(enc*beta) ----
__global__ __launch_bounds__(256) void k2(
    const float* __restrict__ vmean, const float* __restrict__ W_c,
    const float* __restrict__ qc, const float* __restrict__ W_i_hat,
    const float* __restrict__ enc,
    float* __restrict__ beta, unsigned short* __restrict__ abf) {
    __shared__ float qcL[4096];
    __shared__ float sL[64];
    __shared__ float bL[64];
    int blk = blockIdx.x, tid = threadIdx.x;
    #pragma unroll
    for (int i = 0; i < 16; i++) qcL[tid + i * 256] = qc[tid + i * 256];
    __syncthreads();
    int c8 = tid >> 5, lane32 = tid & 31;
    int c = blk * 8 + c8;
    #pragma unroll
    for (int b = 0; b < 8; b++) {
        float v = vmean[b * Cz + c];
        float acc = 0.0f;
        #pragma unroll 4
        for (int i = 0; i < 16; i++) {
            int k = i * 32 + lane32;
            acc += tanhf(fmaf(v, W_c[k], qcL[b * Kz + k])) * W_i_hat[k];
        }
        acc += __shfl_xor(acc, 16); acc += __shfl_xor(acc, 8);
        acc += __shfl_xor(acc, 4);  acc += __shfl_xor(acc, 2);
        acc += __shfl_xor(acc, 1);
        if (lane32 == 0) sL[c8 * 8 + b] = acc;
    }
    __syncthreads();
    if (tid < 64) {
        int c8_ = tid >> 3, b_ = tid & 7;
        float m = -1e30f;
        #pragma unroll
        for (int j = 0; j < 8; j++) m = fmaxf(m, sL[c8_ * 8 + j]);
        float s = 0.0f;
        #pragma unroll
        for (int j = 0; j < 8; j++) s += expf(sL[c8_ * 8 + j] - m);
        float bv = expf(sL[c8_ * 8 + b_] - m) / s;
        beta[b_ * Cz + blk * 8 + c8_] = bv;
        bL[c8_ * 8 + b_] = bv;
    }
    __syncthreads();
    {
        int r = tid >> 2, pq = (tid & 3) * 16;
        int b = r >> 3, c8_ = r & 7;
        int cc = blk * 8 + c8_;
        float bv = bL[c8_ * 8 + b];
        const float* ep = enc + (size_t)(b * Cz + cc) * 64 + pq;
        unsigned short* ap = abf + (size_t)(b * Cz + cc) * 64 + pq;
        #pragma unroll
        for (int q = 0; q < 4; q++) {
            float4 e = *(const float4*)(ep + q * 4);
            ushort4 st = { f2b(e.x * bv), f2b(e.y * bv), f2b(e.z * bv), f2b(e.w * bv) };
            *(ushort4*)(ap + q * 4) = st;
        }
    }
}

// ---- k3: einsum partials spart[cs4][b][p][k] ----
__global__ __launch_bounds__(256) void k3(
    const unsigned short* __restrict__ abf, const unsigned short* __restrict__ wb,
    float* __restrict__ spart) {
    __shared__ __align__(16) float ldsA[4096];
    __shared__ __align__(16) float ldsB[4096];
    int blk = blockIdx.x, tid = threadIdx.x;
    const unsigned short* Ws = wb + O_WS;
    int cs = blk & 3, kt = (blk >> 2) & 7, b = blk >> 5;
    int kq = tid & 15, pq = tid >> 4;
    float acc[4][4] = {};
    for (int chunk = 0; chunk < 8; chunk++) {
        int c0 = cs * 512 + chunk * 64;
        __syncthreads();
        #pragma unroll
        for (int i = 0; i < 2; i++) {
            int run = tid + i * 256;
            int idx = run * 8;
            int cl = idx >> 6, x0 = idx & 63;
            uint4 ua = *(const uint4*)(abf + (size_t)(b * Cz + c0 + cl) * 64 + x0);
            float* dA = ldsA + idx;
            dA[0] = bLO(ua.x); dA[1] = bHI(ua.x); dA[2] = bLO(ua.y); dA[3] = bHI(ua.y);
            dA[4] = bLO(ua.z); dA[5] = bHI(ua.z); dA[6] = bLO(ua.w); dA[7] = bHI(ua.w);
            uint4 ub = *(const uint4*)(Ws + (size_t)(c0 + cl) * Kz + kt * 64 + x0);
            float* dB = ldsB + idx;
            dB[0] = bLO(ub.x); dB[1] = bHI(ub.x); dB[2] = bLO(ub.y); dB[3] = bHI(ub.y);
            dB[4] = bLO(ub.z); dB[5] = bHI(ub.z); dB[6] = bLO(ub.w); dB[7] = bHI(ub.w);
        }
        __syncthreads();
        #pragma unroll 4
        for (int cc = 0; cc < 64; cc++) {
            float4 av = *(const float4*)&ldsA[cc * 64 + pq * 4];
            float4 bv = *(const float4*)&ldsB[cc * 64 + kq * 4];
            acc[0][0] = fmaf(av.x, bv.x, acc[0][0]);
            acc[0][1] = fmaf(av.x, bv.y, acc[0][1]);
            acc[0][2] = fmaf(av.x, bv.z, acc[0][2]);
            acc[0][3] = fmaf(av.x, bv.w, acc[0][3]);
            acc[1][0] = fmaf(av.y, bv.x, acc[1][0]);
            acc[1][1] = fmaf(av.y, bv.y, acc[1][1]);
            acc[1][2] = fmaf(av.y, bv.z, acc[1][2]);
            acc[1][3] = fmaf(av.y, bv.w, acc[1][3]);
            acc[2][0] = fmaf(av.z, bv.x, acc[2][0]);
            acc[2][1] = fmaf(av.z, bv.y, acc[2][1]);
            acc[2][2] = fmaf(av.z, bv.z, acc[2][2]);
            acc[2][3] = fmaf(av.z, bv.w, acc[2][3]);
            acc[3][0] = fmaf(av.w, bv.x, acc[3][0]);
            acc[3][1] = fmaf(av.w, bv.y, acc[3][1]);
            acc[3][2] = fmaf(av.w, bv.z, acc[3][2]);
            acc[3][3] = fmaf(av.w, bv.w, acc[3][3]);
        }
    }
    float* dst = spart + (size_t)((cs * Bz + b) * Pz) * Kz + kt * 64 + kq * 4;
    #pragma unroll
    for (int r = 0; r < 4; r++) {
        float4 w = make_float4(acc[r][0], acc[r][1], acc[r][2], acc[r][3]);
        *(float4*)(dst + (size_t)(pq * 4 + r) * Kz) = w;
    }
}

// ---- k4: spatial scores + batch softmax -> alpha ----
__global__ __launch_bounds__(512) void k4(
    const float* __restrict__ spart, const float* __restrict__ qs,
    const float* __restrict__ W_i, const float* __restrict__ b_i,
    float* __restrict__ alpha) {
    __shared__ float sL[8];
    int blk = blockIdx.x, tid = threadIdx.x;
    int wave = tid >> 6, lane = tid & 63;
    int p = blk, b = wave;
    int k0 = lane * 8;
    float4 q0 = *(const float4*)(qs + b * Kz + k0);
    float4 q1 = *(const float4*)(qs + b * Kz + k0 + 4);
    #pragma unroll
    for (int cs = 0; cs < 4; cs++) {
        const float* sp = spart + (size_t)((cs * Bz + b) * Pz + p) * Kz + k0;
        float4 s0 = *(const float4*)sp;
        float4 s1 = *(const float4*)(sp + 4);
        q0.x += s0.x; q0.y += s0.y; q0.z += s0.z; q0.w += s0.w;
        q1.x += s1.x; q1.y += s1.y; q1.z += s1.z; q1.w += s1.w;
    }
    float4 w0 = *(const float4*)(W_i + k0);
    float4 w1 = *(const float4*)(W_i + k0 + 4);
    float acc = tanhf(q0.x) * w0.x + tanhf(q0.y) * w0.y
              + tanhf(q0.z) * w0.z + tanhf(q0.w) * w0.w
              + tanhf(q1.x) * w1.x + tanhf(q1.y) * w1.y
              + tanhf(q1.z) * w1.z + tanhf(q1.w) * w1.w;
    acc = waveReduce(acc);
    if (lane == 0) sL[b] = acc + b_i[0];
    __syncthreads();
    if (tid < 8) {
        float m = -1e30f;
        #pragma unroll
        for (int j = 0; j < 8; j++) m = fmaxf(m, sL[j]);
        float s = 0.0f;
        #pragma unroll
        for (int j = 0; j < 8; j++) s += expf(sL[j] - m);
        alpha[tid * Pz + p] = expf(sL[tid] - m) / s;
    }
}

// ---- k5: awe[b][c] = beta * mean_p(enc * alpha) ----
__global__ __launch_bounds__(256) void k5(
    const float* __restrict__ enc, const float* __restrict__ beta,
    const float* __restrict__ alpha, float* __restrict__ awe) {
    int blk = blockIdx.x, tid = threadIdx.x;
    int wave = tid >> 6, lane = tid & 63;
    int base = (blk * 4 + wave) * 16;
    float al = alpha[(base >> 11) * Pz + lane];   // b is constant across the 16 rows
    #pragma unroll
    for (int r = 0; r < 16; r++) {
        int w = base + r;
        float v = enc[(size_t)w * 64 + lane] * al;
        v = waveReduce(v);
        if (lane == 0) awe[w] = beta[w] * v * (1.0f / 64.0f);
    }
}

// ---- k6: gates awe-part + cell ----
__global__ __launch_bounds__(256) void k6(
    const float* __restrict__ awe, const float* __restrict__ geh,
    const unsigned short* __restrict__ wb,
    float* __restrict__ h_out, float* __restrict__ c) {
    __shared__ float sred[32];
    int d = blockIdx.x, tid = threadIdx.x;
    int g = tid >> 6, lane = tid & 63;
    int bb = lane >> 3, e8 = lane & 7;
    int j = g * 512 + d;
    const uint4* W4 = (const uint4*)(wb + O_WIH + (size_t)j * 2560 + 512);
    const float4* a4 = (const float4*)(awe + bb * Cz);
    float acc = 0.0f;
    #pragma unroll 8
    for (int i = 0; i < 32; i++) {
        uint4 w = W4[i * 8 + e8];
        float4 x0 = a4[(i * 8 + e8) * 2];
        float4 x1 = a4[(i * 8 + e8) * 2 + 1];
        acc = fmaf(x0.x, bLO(w.x), acc); acc = fmaf(x0.y, bHI(w.x), acc);
        acc = fmaf(x0.z, bLO(w.y), acc); acc = fmaf(x0.w, bHI(w.y), acc);
        acc = fmaf(x1.x, bLO(w.z), acc); acc = fmaf(x1.y, bHI(w.z), acc);
        acc = fmaf(x1.z, bLO(w.w), acc); acc = fmaf(x1.w, bHI(w.w), acc);
    }
    acc += __shfl_xor(acc, 1);
    acc += __shfl_xor(acc, 2);
    acc += __shfl_xor(acc, 4);
    if (e8 == 0) sred[g * 8 + bb] = acc;
    __syncthreads();
    if (tid < 8) {
        int b = tid;
        float gI = sred[b]      + geh[b * 2048 + d];
        float gF = sred[8 + b]  + geh[b * 2048 + 512 + d];
        float gG = sred[16 + b] + geh[b * 2048 + 1024 + d];
        float gO = sred[24 + b] + geh[b * 2048 + 1536 + d];
        float ig = sigf(gI), fg = sigf(gF), gt = tanhf(gG), og = sigf(gO);
        int idx = b * Dz + d;
        float cn = fg * c[idx] + ig * gt;
        c[idx] = cn;
        h_out[idx] = og * tanhf(cn);
    }
}

// ---- lazy host-side stream/event pool (created on first, non-captured call) ----
static hipStream_t g_s2 = nullptr;
static hipEvent_t g_ev[40];
static void ensure_init() {
    if (!g_s2) {
        hipStreamCreateWithFlags(&g_s2, hipStreamNonBlocking);
        for (int i = 0; i < 40; i++)
            hipEventCreateWithFlags(&g_ev[i], hipEventDisableTiming);
    }
}

extern "C" void kernel_launch(void* const* d_in, const int* in_sizes, int n_in,
                              void* d_out, int out_size, void* d_ws, size_t ws_size,
                              hipStream_t stream) {
    ensure_init();
    const float* enc      = (const float*)d_in[0];
    const int*   caps     = (const int*)d_in[1];
    const int*   caplen   = (const int*)d_in[2];
    const float* W_c      = (const float*)d_in[3];
    const float* W_hc     = (const float*)d_in[4];
    const float* W_i_hat  = (const float*)d_in[5];
    const float* b_c      = (const float*)d_in[6];
    const float* W_s      = (const float*)d_in[8];
    const float* W_hs     = (const float*)d_in[9];
    const float* W_i      = (const float*)d_in[10];
    const float* b_s      = (const float*)d_in[11];
    const float* b_i      = (const float*)d_in[12];
    const float* emb      = (const float*)d_in[13];
    const float* W_ih     = (const float*)d_in[14];
    const float* W_hh     = (const float*)d_in[15];
    const float* b_ih     = (const float*)d_in[16];
    const float* b_hh     = (const float*)d_in[17];
    const float* W_init_h = (const float*)d_in[18];
    const float* b_init_h = (const float*)d_in[19];
    const float* W_init_c = (const float*)d_in[20];
    const float* b_init_c = (const float*)d_in[21];
    const float* W_fc     = (const float*)d_in[22];
    const float* b_fc     = (const float*)d_in[23];
    float* out = (float*)d_out;
    float* ws  = (float*)d_ws;

    float* vmean = ws;                       // 16384
    float* hb0   = ws + 16384;               // 4096
    float* hb1   = ws + 20480;               // 4096
    float* c     = ws + 24576;               // 4096
    float* qc    = ws + 28672;               // 4096
    float* qs    = ws + 32768;               // 4096
    float* beta  = ws + 36864;               // 16384
    float* alpha = ws + 53248;               // 512
    float* awe   = ws + 53760;               // 16384
    float* geh   = ws + 70144;               // 16384
    float* spart = ws + 86528;               // 1048576
    unsigned short* abf = (unsigned short*)(ws + 1135104);   // 1 Mi ushorts
    unsigned short* wb  = (unsigned short*)(ws + 1659392);   // 18104320 ushorts

    hipEvent_t* e_main = g_ev;        // [0..12]
    hipEvent_t* e_q    = g_ev + 13;   // [0..11]
    hipEvent_t* e_g    = g_ev + 25;   // [0..11]
    hipEvent_t  e_join = g_ev[37];

    k_prep<<<4353, 256, 0, stream>>>(W_fc, W_ih, W_hh, W_s, W_hc, W_hs,
                                     enc, caps, caplen, wb, vmean, out);
    k_init<<<256, 256, 0, stream>>>(vmean, W_init_h, b_init_h, W_init_c, b_init_c,
                                    hb0, c);
    hipEventRecord(e_main[0], stream);

    for (int t = 0; t < Tz; t++) {
        float* h_in  = (t & 1) ? hb1 : hb0;
        float* h_out = (t & 1) ? hb0 : hb1;

        // ---- stream 2: h-only dependents ----
        hipStreamWaitEvent(g_s2, e_main[t], 0);
        k_qcqs<<<16, 256, 0, g_s2>>>(h_in, wb, b_c, b_s, qc, qs);
        hipEventRecord(e_q[t], g_s2);
        k_geh<<<512, 256, 0, g_s2>>>(h_in, emb, caps, wb, b_ih, b_hh, geh, t);
        hipEventRecord(e_g[t], g_s2);
        if (t > 0)
            k_preds<<<1250, 256, 0, g_s2>>>(h_in, wb, b_fc, out, t - 1);

        // ---- main chain ----
        hipStreamWaitEvent(stream, e_q[t], 0);
        k2<<<256, 256, 0, stream>>>(vmean, W_c, qc, W_i_hat, enc, beta, abf);
        k3<<<256, 256, 0, stream>>>(abf, wb, spart);
        k4<<<64, 512, 0, stream>>>(spart, qs, W_i, b_i, alpha);
        k5<<<256, 256, 0, stream>>>(enc, beta, alpha, awe);
        hipStreamWaitEvent(stream, e_g[t], 0);
        k6<<<512, 256, 0, stream>>>(awe, geh, wb, h_out, c);
        hipEventRecord(e_main[t + 1], stream);
    }

    // final preds on s2, then join
    hipStreamWaitEvent(g_s2, e_main[Tz], 0);
    k_preds<<<1250, 256, 0, g_s2>>>(hb0, wb, b_fc, out, Tz - 1);
    hipEventRecord(e_join, g_s2);
    hipStreamWaitEvent(stream, e_join, 0);
}